// Round 1
// baseline (686.782 us; speedup 1.0000x reference)
//
#include <hip/hip_runtime.h>
#include <math.h>

// Problem constants (LocallyEnhancedAttention: B=16, N=3136, C=256, SR=7, HEADS=8)
#define B_     16
#define H_IMG  56
#define W_IMG  56
#define N_TOK  3136      // 56*56
#define C_     256
#define C4_    64        // C_/4
#define NHEAD  8
#define HDIM   32
#define NCH    8         // attn pixel chunks (each = 7 image rows = 392 pixels)

__device__ __forceinline__ float geluf(float x) {
    // jax.nn.gelu(approximate=False) = x * 0.5 * (1 + erf(x/sqrt(2)))
    return 0.5f * x * (1.0f + erff(x * 0.70710678118654752f));
}

// 8 -> 56 bilinear (half-pixel + edge renormalize == index clamp).
// fy = (o+0.5)/7 - 0.5 = (o-3)/7
__device__ __forceinline__ void up_coef(int o, int& i0, int& i1, float& t) {
    float f  = (float)(o - 3) * (1.0f / 7.0f);
    float fl = floorf(f);
    int   ii = (int)fl;
    t = f - fl;
    if (ii < 0)       { i0 = 0; i1 = 0; t = 0.0f; }
    else if (ii >= 7) { i0 = 7; i1 = 7; t = 0.0f; }
    else              { i0 = ii; i1 = ii + 1; }
}

// ---------------------------------------------------------------------------
// GEMM (NT): C[m,n] = sum_k A[m,k] * Bm[n,k] (+ bias[n])
// BM=BN=128, BK=16, 256 threads, 8x8 micro-tile.
// ---------------------------------------------------------------------------
__global__ __launch_bounds__(256) void gemm_nt_kernel(
    const float* __restrict__ A,    // [M][K]
    const float* __restrict__ Bm,   // [N][K]
    const float* __restrict__ bias, // [N] or nullptr
    float* __restrict__ C,          // [M][N]
    int M, int N, int K)
{
    __shared__ float As[16][132];
    __shared__ float Bs[16][132];
    const int tid = threadIdx.x;
    const int nb  = N >> 7;              // N/128
    const int bx  = blockIdx.x % nb;
    const int by  = blockIdx.x / nb;
    const int lr  = tid >> 2;            // 0..63
    const int lc  = (tid & 3) << 2;      // 0,4,8,12
    const float* Ap = A + (size_t)(by * 128 + lr) * K + lc;
    const float* Bp = Bm + (size_t)(bx * 128 + lr) * K + lc;
    const int ty = tid >> 4;             // 0..15
    const int tx = tid & 15;             // 0..15

    float acc[8][8];
#pragma unroll
    for (int i = 0; i < 8; ++i)
#pragma unroll
        for (int j = 0; j < 8; ++j) acc[i][j] = 0.0f;

    for (int k0 = 0; k0 < K; k0 += 16) {
        float4 a0 = *(const float4*)(Ap + k0);
        float4 a1 = *(const float4*)(Ap + (size_t)64 * K + k0);
        float4 b0 = *(const float4*)(Bp + k0);
        float4 b1 = *(const float4*)(Bp + (size_t)64 * K + k0);
        __syncthreads();
        As[lc + 0][lr]      = a0.x; As[lc + 1][lr]      = a0.y;
        As[lc + 2][lr]      = a0.z; As[lc + 3][lr]      = a0.w;
        As[lc + 0][lr + 64] = a1.x; As[lc + 1][lr + 64] = a1.y;
        As[lc + 2][lr + 64] = a1.z; As[lc + 3][lr + 64] = a1.w;
        Bs[lc + 0][lr]      = b0.x; Bs[lc + 1][lr]      = b0.y;
        Bs[lc + 2][lr]      = b0.z; Bs[lc + 3][lr]      = b0.w;
        Bs[lc + 0][lr + 64] = b1.x; Bs[lc + 1][lr + 64] = b1.y;
        Bs[lc + 2][lr + 64] = b1.z; Bs[lc + 3][lr + 64] = b1.w;
        __syncthreads();
#pragma unroll
        for (int kk = 0; kk < 16; ++kk) {
            float4 av0 = *(const float4*)&As[kk][ty * 8];
            float4 av1 = *(const float4*)&As[kk][ty * 8 + 4];
            float4 bv0 = *(const float4*)&Bs[kk][tx * 8];
            float4 bv1 = *(const float4*)&Bs[kk][tx * 8 + 4];
            float a_[8] = {av0.x, av0.y, av0.z, av0.w, av1.x, av1.y, av1.z, av1.w};
            float b_[8] = {bv0.x, bv0.y, bv0.z, bv0.w, bv1.x, bv1.y, bv1.z, bv1.w};
#pragma unroll
            for (int i = 0; i < 8; ++i)
#pragma unroll
                for (int j = 0; j < 8; ++j)
                    acc[i][j] = fmaf(a_[i], b_[j], acc[i][j]);
        }
    }

    const int col = bx * 128 + tx * 8;
    float bv[8];
#pragma unroll
    for (int j = 0; j < 8; ++j) bv[j] = bias ? bias[col + j] : 0.0f;
#pragma unroll
    for (int i = 0; i < 8; ++i) {
        int row = by * 128 + ty * 8 + i;
        float4 o0 = make_float4(acc[i][0] + bv[0], acc[i][1] + bv[1],
                                acc[i][2] + bv[2], acc[i][3] + bv[3]);
        float4 o1 = make_float4(acc[i][4] + bv[4], acc[i][5] + bv[5],
                                acc[i][6] + bv[6], acc[i][7] + bv[7]);
        *(float4*)&C[(size_t)row * N + col]     = o0;
        *(float4*)&C[(size_t)row * N + col + 4] = o1;
    }
}

// ---------------------------------------------------------------------------
// Depthwise 3x3 conv (SAME, zero pad) + eval BatchNorm, NHWC. Optional add.
// One thread = one float4 of channels at one pixel.
// ---------------------------------------------------------------------------
__global__ __launch_bounds__(256) void dwconv_bn_kernel(
    const float* __restrict__ in,   // [B][56][56][C]
    const float* __restrict__ w,    // [C][9]
    const float* __restrict__ gg, const float* __restrict__ bb,
    const float* __restrict__ mm, const float* __restrict__ vv,
    const float* __restrict__ add_, // [B][56][56][C] or nullptr (added post-BN)
    float* __restrict__ out)
{
    int idx = blockIdx.x * 256 + threadIdx.x;     // 0 .. B*N*C4-1
    int c4  = idx % C4_;
    int pix = idx / C4_;
    int x   = pix % W_IMG;
    int y   = (pix / W_IMG) % H_IMG;
    int b   = pix / (W_IMG * H_IMG);
    if (b >= B_) return;
    int c0 = c4 * 4;

    float ax = 0.f, ay = 0.f, az = 0.f, aw = 0.f;
#pragma unroll
    for (int ky = 0; ky < 3; ++ky) {
        int yy = y + ky - 1;
        if (yy < 0 || yy >= H_IMG) continue;
#pragma unroll
        for (int kx = 0; kx < 3; ++kx) {
            int xx = x + kx - 1;
            if (xx < 0 || xx >= W_IMG) continue;
            const float4 iv = *(const float4*)(in + (((size_t)(b * H_IMG + yy) * W_IMG + xx) * C_ + c0));
            int t = ky * 3 + kx;
            float w0 = __ldg(w + (c0 + 0) * 9 + t);
            float w1 = __ldg(w + (c0 + 1) * 9 + t);
            float w2 = __ldg(w + (c0 + 2) * 9 + t);
            float w3 = __ldg(w + (c0 + 3) * 9 + t);
            ax = fmaf(iv.x, w0, ax);
            ay = fmaf(iv.y, w1, ay);
            az = fmaf(iv.z, w2, az);
            aw = fmaf(iv.w, w3, aw);
        }
    }
    const float4 gv = *(const float4*)(gg + c0);
    const float4 bv = *(const float4*)(bb + c0);
    const float4 mv = *(const float4*)(mm + c0);
    const float4 vrv = *(const float4*)(vv + c0);
    float s0 = gv.x * rsqrtf(vrv.x + 1e-5f);
    float s1 = gv.y * rsqrtf(vrv.y + 1e-5f);
    float s2 = gv.z * rsqrtf(vrv.z + 1e-5f);
    float s3 = gv.w * rsqrtf(vrv.w + 1e-5f);
    float o0 = ax * s0 + (bv.x - mv.x * s0);
    float o1 = ay * s1 + (bv.y - mv.y * s1);
    float o2 = az * s2 + (bv.z - mv.z * s2);
    float o3 = aw * s3 + (bv.w - mv.w * s3);
    if (add_) {
        const float4 av = *(const float4*)(add_ + (size_t)idx * 4);
        o0 += av.x; o1 += av.y; o2 += av.z; o3 += av.w;
    }
    *(float4*)(out + (size_t)idx * 4) = make_float4(o0, o1, o2, o3);
}

// ---------------------------------------------------------------------------
// 7x7 avg pool, NHWC: [B][56][56][C] -> [B][64][C]
// ---------------------------------------------------------------------------
__global__ __launch_bounds__(256) void avgpool7_kernel(
    const float* __restrict__ in, float* __restrict__ out)
{
    int idx = blockIdx.x * 256 + threadIdx.x;     // 0 .. B*64*C4-1
    int c4 = idx % C4_;
    int g  = (idx / C4_) % 64;
    int b  = idx / (C4_ * 64);
    if (b >= B_) return;
    int yy = g >> 3, xx = g & 7;
    float ax = 0.f, ay = 0.f, az = 0.f, aw = 0.f;
    for (int i = 0; i < 7; ++i)
        for (int j = 0; j < 7; ++j) {
            const float4 iv = *(const float4*)(in +
                (((size_t)(b * H_IMG + yy * 7 + i) * W_IMG + xx * 7 + j) * C_ + c4 * 4));
            ax += iv.x; ay += iv.y; az += iv.z; aw += iv.w;
        }
    const float r = 1.0f / 49.0f;
    *(float4*)(out + (((size_t)b * 64 + g) * C_ + c4 * 4)) =
        make_float4(ax * r, ay * r, az * r, aw * r);
}

// ---------------------------------------------------------------------------
// In-place GELU (exact), float4.
// ---------------------------------------------------------------------------
__global__ __launch_bounds__(256) void gelu_inplace_kernel(float* __restrict__ p, int n4)
{
    int idx = blockIdx.x * 256 + threadIdx.x;
    if (idx >= n4) return;
    float4 v = ((float4*)p)[idx];
    v.x = geluf(v.x); v.y = geluf(v.y); v.z = geluf(v.z); v.w = geluf(v.w);
    ((float4*)p)[idx] = v;
}

// ---------------------------------------------------------------------------
// Per-(b,head) logits: A[i][j] = scale * dot32(q[b,i,h*32:], k[b,j,h*32:])
// ---------------------------------------------------------------------------
__global__ __launch_bounds__(256) void qk_kernel(
    const float* __restrict__ q,   // [B][64][C]
    const float* __restrict__ k,   // [B][64][C]
    float* __restrict__ attnL)     // [B*8][64][64]
{
    int bh = blockIdx.x;
    int b = bh >> 3, head = bh & 7;
    __shared__ float qs[64][33];
    __shared__ float ks[64][33];
    int tid = threadIdx.x;
    for (int t = tid; t < 512; t += 256) {
        int i = t >> 3, dq = (t & 7) * 4;
        const float4 qv = *(const float4*)(q + ((size_t)(b * 64 + i) * C_ + head * 32 + dq));
        const float4 kv = *(const float4*)(k + ((size_t)(b * 64 + i) * C_ + head * 32 + dq));
        qs[i][dq + 0] = qv.x; qs[i][dq + 1] = qv.y; qs[i][dq + 2] = qv.z; qs[i][dq + 3] = qv.w;
        ks[i][dq + 0] = kv.x; ks[i][dq + 1] = kv.y; ks[i][dq + 2] = kv.z; ks[i][dq + 3] = kv.w;
    }
    __syncthreads();
    int i  = tid >> 2;
    int jb = (tid & 3) * 16;
    float qr[32];
#pragma unroll
    for (int d = 0; d < 32; ++d) qr[d] = qs[i][d];
    float* outp = attnL + (size_t)bh * 4096 + i * 64 + jb;
#pragma unroll
    for (int j = 0; j < 16; ++j) {
        float s = 0.f;
#pragma unroll
        for (int d = 0; d < 32; ++d) s = fmaf(qr[d], ks[jb + j][d], s);
        outp[j] = s * 0.0625f;   // C^-0.5 = 1/16
    }
}

// ---------------------------------------------------------------------------
// Fused upsample(logits)->softmax-weights->PV partial sums.
// Block = (b, head, chunk of 7 image rows). Threads: 64 rows x 4 d-groups.
// Row max of upsampled logits == row max of raw logits (grid points exact,
// interp is convex) -> single pass, accumulate Z and o simultaneously.
// ---------------------------------------------------------------------------
__global__ __launch_bounds__(256) void attn_pv_kernel(
    const float* __restrict__ attnL,  // [BH][64][64]
    const float* __restrict__ v,      // [B][3136][256]
    float* __restrict__ part_o,       // [BH][NCH][64][32]
    float* __restrict__ part_z)       // [BH][NCH][64]
{
    int blk   = blockIdx.x;
    int chunk = blk % NCH;
    int bh    = blk / NCH;
    int b = bh >> 3, head = bh & 7;
    __shared__ float Al[64][64];
    __shared__ float mrow[64];
    __shared__ float RY[64][10];      // [i][0..8], entry 8 duplicates 7
    __shared__ float Vrow[56][32];
    __shared__ float txs[56];
    __shared__ int   x0s[56];
    int tid = threadIdx.x;

    {
        const float4* src = (const float4*)(attnL + (size_t)bh * 4096);
        float4* dst = (float4*)&Al[0][0];
        for (int t = tid; t < 1024; t += 256) dst[t] = src[t];
    }
    if (tid < 56) {
        int i0, i1; float t;
        up_coef(tid, i0, i1, t);
        x0s[tid] = i0;   // value = (1-t)*R[i0] + t*R[i0+1]; edges have t=0
        txs[tid] = t;
    }
    __syncthreads();
    if (tid < 64) {
        float m = Al[tid][0];
        for (int j = 1; j < 64; ++j) m = fmaxf(m, Al[tid][j]);
        mrow[tid] = m;
    }
    __syncthreads();

    int i  = tid >> 2;   // query row 0..63
    int dg = tid & 3;    // d-group (8 channels each)
    float4 o0 = make_float4(0,0,0,0), o1 = make_float4(0,0,0,0);
    float z = 0.f;

    for (int r = 0; r < 7; ++r) {
        int y = chunk * 7 + r;
        __syncthreads();   // protect Vrow/RY from previous iteration readers
        for (int t = tid; t < 448; t += 256) {
            int xx = t >> 3, dq = (t & 7) << 2;
            *(float4*)&Vrow[xx][dq] =
                *(const float4*)(v + ((size_t)b * N_TOK + y * W_IMG + xx) * C_ + head * 32 + dq);
        }
        int y0, y1; float ty;
        up_coef(y, y0, y1, ty);
        for (int kk = dg; kk < 9; kk += 4) {
            int ks = kk < 8 ? kk : 7;
            float a0 = Al[i][y0 * 8 + ks];
            float a1 = Al[i][y1 * 8 + ks];
            RY[i][kk] = a0 + ty * (a1 - a0) - mrow[i];
        }
        __syncthreads();
        for (int x = 0; x < 56; ++x) {
            float tx = txs[x];
            int   x0 = x0s[x];
            float r0 = RY[i][x0], r1 = RY[i][x0 + 1];
            float l = r0 + tx * (r1 - r0);
            float wgt = __expf(l);
            z += wgt;
            const float4 v0 = *(const float4*)&Vrow[x][dg * 8];
            const float4 v1 = *(const float4*)&Vrow[x][dg * 8 + 4];
            o0.x = fmaf(wgt, v0.x, o0.x); o0.y = fmaf(wgt, v0.y, o0.y);
            o0.z = fmaf(wgt, v0.z, o0.z); o0.w = fmaf(wgt, v0.w, o0.w);
            o1.x = fmaf(wgt, v1.x, o1.x); o1.y = fmaf(wgt, v1.y, o1.y);
            o1.z = fmaf(wgt, v1.z, o1.z); o1.w = fmaf(wgt, v1.w, o1.w);
        }
    }

    size_t base = (((size_t)bh * NCH + chunk) * 64 + i) * 32 + dg * 8;
    *(float4*)(part_o + base)     = o0;
    *(float4*)(part_o + base + 4) = o1;
    if (dg == 0) part_z[((size_t)bh * NCH + chunk) * 64 + i] = z;
}

// ---------------------------------------------------------------------------
// Combine partials -> o_small [B][64][C] (NHWC, c = head*32+d), divide by Z.
// ---------------------------------------------------------------------------
__global__ __launch_bounds__(256) void combine_kernel(
    const float* __restrict__ part_o, const float* __restrict__ part_z,
    float* __restrict__ o_small)
{
    int idx = blockIdx.x * 256 + threadIdx.x;  // B*64*C
    if (idx >= B_ * 64 * C_) return;
    int c = idx % C_;
    int g = (idx / C_) % 64;
    int b = idx / (C_ * 64);
    int head = c >> 5, d = c & 31;
    int bh = b * 8 + head;
    float oo = 0.f, zz = 0.f;
    for (int ch = 0; ch < NCH; ++ch) {
        oo += part_o[(((size_t)bh * NCH + ch) * 64 + g) * 32 + d];
        zz += part_z[((size_t)bh * NCH + ch) * 64 + g];
    }
    o_small[idx] = oo / zz;
}

// ---------------------------------------------------------------------------
// Bilinear upsample 8x8 -> 56x56, NHWC.
// ---------------------------------------------------------------------------
__global__ __launch_bounds__(256) void upsample7_kernel(
    const float* __restrict__ in,   // [B][8][8][C]
    float* __restrict__ out)        // [B][56][56][C]
{
    int idx = blockIdx.x * 256 + threadIdx.x;  // per float4
    int c4  = idx % C4_;
    int pix = idx / C4_;
    int x = pix % W_IMG;
    int y = (pix / W_IMG) % H_IMG;
    int b = pix / (W_IMG * H_IMG);
    if (b >= B_) return;
    int y0, y1, x0, x1; float ty, tx;
    up_coef(y, y0, y1, ty);
    up_coef(x, x0, x1, tx);
    const float* base = in + (size_t)b * 64 * C_ + c4 * 4;
    const float4 v00 = *(const float4*)(base + (y0 * 8 + x0) * C_);
    const float4 v01 = *(const float4*)(base + (y0 * 8 + x1) * C_);
    const float4 v10 = *(const float4*)(base + (y1 * 8 + x0) * C_);
    const float4 v11 = *(const float4*)(base + (y1 * 8 + x1) * C_);
    float r0x = v00.x + tx * (v01.x - v00.x), r1x = v10.x + tx * (v11.x - v10.x);
    float r0y = v00.y + tx * (v01.y - v00.y), r1y = v10.y + tx * (v11.y - v10.y);
    float r0z = v00.z + tx * (v01.z - v00.z), r1z = v10.z + tx * (v11.z - v10.z);
    float r0w = v00.w + tx * (v01.w - v00.w), r1w = v10.w + tx * (v11.w - v10.w);
    *(float4*)(out + (size_t)idx * 4) = make_float4(
        r0x + ty * (r1x - r0x), r0y + ty * (r1y - r0y),
        r0z + ty * (r1z - r0z), r0w + ty * (r1w - r0w));
}

// ---------------------------------------------------------------------------
extern "C" void kernel_launch(void* const* d_in, const int* in_sizes, int n_in,
                              void* d_out, int out_size, void* d_ws, size_t ws_size,
                              hipStream_t stream)
{
    const float* x    = (const float*)d_in[0];
    const float* Wv   = (const float*)d_in[1];
    const float* c1w  = (const float*)d_in[2];
    const float* b1g  = (const float*)d_in[3];
    const float* b1b  = (const float*)d_in[4];
    const float* b1m  = (const float*)d_in[5];
    const float* b1v  = (const float*)d_in[6];
    const float* c2w  = (const float*)d_in[7];
    const float* b2g  = (const float*)d_in[8];
    const float* b2b  = (const float*)d_in[9];
    const float* b2m  = (const float*)d_in[10];
    const float* b2v  = (const float*)d_in[11];
    const float* vupw = (const float*)d_in[12];
    const float* b3g  = (const float*)d_in[13];
    const float* b3b  = (const float*)d_in[14];
    const float* b3m  = (const float*)d_in[15];
    const float* b3v  = (const float*)d_in[16];
    const float* Wp   = (const float*)d_in[17];
    const float* bp   = (const float*)d_in[18];
    float* out = (float*)d_out;
    float* ws  = (float*)d_ws;

    const size_t SZ = (size_t)B_ * N_TOK * C_;      // 12,845,056 floats
    float* v       = ws;
    float* s1      = v  + SZ;
    float* s2      = s1 + SZ;
    float* q       = s2 + SZ;                        // B*64*C
    float* kk      = q  + (size_t)B_ * 64 * C_;
    float* attnL   = kk + (size_t)B_ * 64 * C_;      // B*8*64*64
    float* part_o  = attnL  + (size_t)B_ * 8 * 64 * 64;
    float* part_z  = part_o + (size_t)B_ * 8 * NCH * 64 * 32;
    float* o_small = part_z + (size_t)B_ * 8 * NCH * 64;

    const int M = B_ * N_TOK;                        // 50176
    const int pix_blocks = B_ * N_TOK / 4;           // 12544 (B*N*C4/256)

    // 1. v = x @ Wv^T
    gemm_nt_kernel<<<(M / 128) * (C_ / 128), 256, 0, stream>>>(x, Wv, nullptr, v, M, C_, C_);
    // 2. s1 = bn1(dwconv(v))
    dwconv_bn_kernel<<<pix_blocks, 256, 0, stream>>>(v, c1w, b1g, b1b, b1m, b1v, nullptr, s1);
    // 3. q = avgpool7(s1)
    avgpool7_kernel<<<B_ * 64 * C4_ / 256, 256, 0, stream>>>(s1, q);
    // 4. s1 <- gelu(s1)
    gelu_inplace_kernel<<<pix_blocks, 256, 0, stream>>>(s1, (int)(SZ / 4));
    // 5. s2 = bn2(dwconv(gelu(s1)))
    dwconv_bn_kernel<<<pix_blocks, 256, 0, stream>>>(s1, c2w, b2g, b2b, b2m, b2v, nullptr, s2);
    // 6. k = avgpool7(s2)
    avgpool7_kernel<<<B_ * 64 * C4_ / 256, 256, 0, stream>>>(s2, kk);
    // 7. s2 <- gelu(s2)  (= skip_tok)
    gelu_inplace_kernel<<<pix_blocks, 256, 0, stream>>>(s2, (int)(SZ / 4));
    // 8. logits (scaled)
    qk_kernel<<<B_ * 8, 256, 0, stream>>>(q, kk, attnL);
    // 9. fused upsample+softmax-weights+PV partials
    attn_pv_kernel<<<B_ * 8 * NCH, 256, 0, stream>>>(attnL, v, part_o, part_z);
    // 10. combine -> o_small [B][8][8][C]
    combine_kernel<<<B_ * 64 * C_ / 256, 256, 0, stream>>>(part_o, part_z, o_small);
    // 11. upsample o_small -> full res (reuse s1)
    upsample7_kernel<<<pix_blocks, 256, 0, stream>>>(o_small, s1);
    // 12. t = bn3(dwconv(up)) + gelu(s2)   (reuse v)
    dwconv_bn_kernel<<<pix_blocks, 256, 0, stream>>>(s1, vupw, b3g, b3b, b3m, b3v, s2, v);
    // 13. out = t @ Wp^T + bp
    gemm_nt_kernel<<<(M / 128) * (C_ / 128), 256, 0, stream>>>(v, Wp, bp, out, M, C_, C_);
}

// Round 2
// 475.108 us; speedup vs baseline: 1.4455x; 1.4455x over previous
//
#include <hip/hip_runtime.h>
#include <math.h>

// Problem constants (LocallyEnhancedAttention: B=16, N=3136, C=256, SR=7, HEADS=8)
#define B_     16
#define H_IMG  56
#define W_IMG  56
#define N_TOK  3136      // 56*56
#define C_     256
#define C4_    64        // C_/4
#define NHEAD  8
#define HDIM   32
#define NCH    8         // attn pixel chunks (each = 7 image rows = 392 pixels)

__device__ __forceinline__ float geluf(float x) {
    // jax.nn.gelu(approximate=False) = x * 0.5 * (1 + erf(x/sqrt(2)))
    return 0.5f * x * (1.0f + erff(x * 0.70710678118654752f));
}

// 8 -> 56 bilinear (half-pixel + edge renormalize == index clamp).
// f = (o-3)/7
__device__ __forceinline__ void up_coef(int o, int& i0, int& i1, float& t) {
    float f  = (float)(o - 3) * (1.0f / 7.0f);
    float fl = floorf(f);
    int   ii = (int)fl;
    t = f - fl;
    if (ii < 0)       { i0 = 0; i1 = 0; t = 0.0f; }
    else if (ii >= 7) { i0 = 7; i1 = 7; t = 0.0f; }
    else              { i0 = ii; i1 = ii + 1; }
}

// ---------------------------------------------------------------------------
// Prep: transpose dw weights [C][9] -> [9][C]; fold BN into scale/shift.
// ---------------------------------------------------------------------------
__global__ void prep_kernel(
    const float* __restrict__ w1, const float* __restrict__ w2, const float* __restrict__ w3,
    const float* __restrict__ g1, const float* __restrict__ b1, const float* __restrict__ m1, const float* __restrict__ v1,
    const float* __restrict__ g2, const float* __restrict__ b2, const float* __restrict__ m2, const float* __restrict__ v2,
    const float* __restrict__ g3, const float* __restrict__ b3, const float* __restrict__ m3, const float* __restrict__ v3,
    float* __restrict__ wT1, float* __restrict__ wT2, float* __restrict__ wT3,
    float* __restrict__ sc1, float* __restrict__ sh1,
    float* __restrict__ sc2, float* __restrict__ sh2,
    float* __restrict__ sc3, float* __restrict__ sh3)
{
    int c = threadIdx.x;   // 256 threads, 1 block
#pragma unroll
    for (int t = 0; t < 9; ++t) {
        wT1[t * C_ + c] = w1[c * 9 + t];
        wT2[t * C_ + c] = w2[c * 9 + t];
        wT3[t * C_ + c] = w3[c * 9 + t];
    }
    float s1 = g1[c] * rsqrtf(v1[c] + 1e-5f); sc1[c] = s1; sh1[c] = b1[c] - m1[c] * s1;
    float s2 = g2[c] * rsqrtf(v2[c] + 1e-5f); sc2[c] = s2; sh2[c] = b2[c] - m2[c] * s2;
    float s3 = g3[c] * rsqrtf(v3[c] + 1e-5f); sc3[c] = s3; sh3[c] = b3[c] - m3[c] * s3;
}

// ---------------------------------------------------------------------------
// GEMM (NT): C[m,n] = sum_k A[m,k] * Bm[n,k] (+ bias[n])
// BM=BN=128, BK=16, 256 threads, 8x8 micro-tile.
// ---------------------------------------------------------------------------
__global__ __launch_bounds__(256) void gemm_nt_kernel(
    const float* __restrict__ A,    // [M][K]
    const float* __restrict__ Bm,   // [N][K]
    const float* __restrict__ bias, // [N] or nullptr
    float* __restrict__ C,          // [M][N]
    int M, int N, int K)
{
    __shared__ float As[16][132];
    __shared__ float Bs[16][132];
    const int tid = threadIdx.x;
    const int nb  = N >> 7;              // N/128
    const int bx  = blockIdx.x % nb;
    const int by  = blockIdx.x / nb;
    const int lr  = tid >> 2;            // 0..63
    const int lc  = (tid & 3) << 2;      // 0,4,8,12
    const float* Ap = A + (size_t)(by * 128 + lr) * K + lc;
    const float* Bp = Bm + (size_t)(bx * 128 + lr) * K + lc;
    const int ty = tid >> 4;             // 0..15
    const int tx = tid & 15;             // 0..15

    float acc[8][8];
#pragma unroll
    for (int i = 0; i < 8; ++i)
#pragma unroll
        for (int j = 0; j < 8; ++j) acc[i][j] = 0.0f;

    for (int k0 = 0; k0 < K; k0 += 16) {
        float4 a0 = *(const float4*)(Ap + k0);
        float4 a1 = *(const float4*)(Ap + (size_t)64 * K + k0);
        float4 b0 = *(const float4*)(Bp + k0);
        float4 b1 = *(const float4*)(Bp + (size_t)64 * K + k0);
        __syncthreads();
        As[lc + 0][lr]      = a0.x; As[lc + 1][lr]      = a0.y;
        As[lc + 2][lr]      = a0.z; As[lc + 3][lr]      = a0.w;
        As[lc + 0][lr + 64] = a1.x; As[lc + 1][lr + 64] = a1.y;
        As[lc + 2][lr + 64] = a1.z; As[lc + 3][lr + 64] = a1.w;
        Bs[lc + 0][lr]      = b0.x; Bs[lc + 1][lr]      = b0.y;
        Bs[lc + 2][lr]      = b0.z; Bs[lc + 3][lr]      = b0.w;
        Bs[lc + 0][lr + 64] = b1.x; Bs[lc + 1][lr + 64] = b1.y;
        Bs[lc + 2][lr + 64] = b1.z; Bs[lc + 3][lr + 64] = b1.w;
        __syncthreads();
#pragma unroll
        for (int kk = 0; kk < 16; ++kk) {
            float4 av0 = *(const float4*)&As[kk][ty * 8];
            float4 av1 = *(const float4*)&As[kk][ty * 8 + 4];
            float4 bv0 = *(const float4*)&Bs[kk][tx * 8];
            float4 bv1 = *(const float4*)&Bs[kk][tx * 8 + 4];
            float a_[8] = {av0.x, av0.y, av0.z, av0.w, av1.x, av1.y, av1.z, av1.w};
            float b_[8] = {bv0.x, bv0.y, bv0.z, bv0.w, bv1.x, bv1.y, bv1.z, bv1.w};
#pragma unroll
            for (int i = 0; i < 8; ++i)
#pragma unroll
                for (int j = 0; j < 8; ++j)
                    acc[i][j] = fmaf(a_[i], b_[j], acc[i][j]);
        }
    }

    const int col = bx * 128 + tx * 8;
    float bv[8];
#pragma unroll
    for (int j = 0; j < 8; ++j) bv[j] = bias ? bias[col + j] : 0.0f;
#pragma unroll
    for (int i = 0; i < 8; ++i) {
        int row = by * 128 + ty * 8 + i;
        float4 o0 = make_float4(acc[i][0] + bv[0], acc[i][1] + bv[1],
                                acc[i][2] + bv[2], acc[i][3] + bv[3]);
        float4 o1 = make_float4(acc[i][4] + bv[4], acc[i][5] + bv[5],
                                acc[i][6] + bv[6], acc[i][7] + bv[7]);
        *(float4*)&C[(size_t)row * N + col]     = o0;
        *(float4*)&C[(size_t)row * N + col + 4] = o1;
    }
}

// ---------------------------------------------------------------------------
// Fused: dwconv3x3 + BN, then (a) 7x7 avgpool of the BN output (pre-gelu)
// accumulated in LDS -> pool_out, and (b) gelu(BN output) -> outg (full res).
// Block = (b, gy, gx-pair): 7 rows x 14 cols x 64 c4-groups. 256 threads:
// wave = one pixel's 64 channel-quads -> weights/BN live in registers.
// ---------------------------------------------------------------------------
__global__ __launch_bounds__(256) void dwconv_bn_pool_gelu_kernel(
    const float* __restrict__ in,     // [B][56][56][C]
    const float* __restrict__ wT,     // [9][C]
    const float* __restrict__ scv,    // [C]
    const float* __restrict__ shv,    // [C]
    float* __restrict__ outg,         // [B][56][56][C]  gelu(bn(conv))
    float* __restrict__ pool)         // [B][64][C]      avgpool of bn(conv)
{
    const int blk = blockIdx.x;
    const int gxp = blk & 3;
    const int gy  = (blk >> 2) & 7;
    const int b   = blk >> 5;
    const int tid = threadIdx.x;
    const int c4  = tid & 63;
    const int wv  = tid >> 6;
    const int c0  = c4 * 4;

    float4 wr[9];
#pragma unroll
    for (int t = 0; t < 9; ++t) wr[t] = *(const float4*)(wT + t * C_ + c0);
    const float4 sc = *(const float4*)(scv + c0);
    const float4 sh = *(const float4*)(shv + c0);

    const int x0 = gxp * 14, y0 = gy * 7;
    const float* inb = in + (size_t)b * N_TOK * C_;
    float4 a0 = make_float4(0, 0, 0, 0), a1 = make_float4(0, 0, 0, 0);

    for (int p = wv; p < 98; p += 4) {
        int py = p / 14, px = p - py * 14;
        int y = y0 + py, x = x0 + px;
        float cx = 0.f, cy = 0.f, cz = 0.f, cw = 0.f;
#pragma unroll
        for (int dy = -1; dy <= 1; ++dy) {
            int yy = y + dy;
            if (yy < 0 || yy >= H_IMG) continue;
#pragma unroll
            for (int dx = -1; dx <= 1; ++dx) {
                int xx = x + dx;
                if (xx < 0 || xx >= W_IMG) continue;
                const float4 iv = *(const float4*)(inb + (size_t)(yy * W_IMG + xx) * C_ + c0);
                const float4 w  = wr[(dy + 1) * 3 + (dx + 1)];
                cx = fmaf(iv.x, w.x, cx);
                cy = fmaf(iv.y, w.y, cy);
                cz = fmaf(iv.z, w.z, cz);
                cw = fmaf(iv.w, w.w, cw);
            }
        }
        float vx = cx * sc.x + sh.x;
        float vy = cy * sc.y + sh.y;
        float vz = cz * sc.z + sh.z;
        float vw = cw * sc.w + sh.w;
        if (px < 7) { a0.x += vx; a0.y += vy; a0.z += vz; a0.w += vw; }
        else        { a1.x += vx; a1.y += vy; a1.z += vz; a1.w += vw; }
        *(float4*)(outg + ((size_t)b * N_TOK + y * W_IMG + x) * C_ + c0) =
            make_float4(geluf(vx), geluf(vy), geluf(vz), geluf(vw));
    }

    __shared__ float4 ps[4][2][64];
    ps[wv][0][c4] = a0;
    ps[wv][1][c4] = a1;
    __syncthreads();
    if (tid < 128) {
        int wi = tid >> 6, cc = tid & 63;
        float4 s  = ps[0][wi][cc];
        float4 t1 = ps[1][wi][cc];
        float4 t2 = ps[2][wi][cc];
        float4 t3 = ps[3][wi][cc];
        const float r = 1.0f / 49.0f;
        int g = gy * 8 + gxp * 2 + wi;
        *(float4*)(pool + ((size_t)b * 64 + g) * C_ + cc * 4) = make_float4(
            (s.x + t1.x + t2.x + t3.x) * r, (s.y + t1.y + t2.y + t3.y) * r,
            (s.z + t1.z + t2.z + t3.z) * r, (s.w + t1.w + t2.w + t3.w) * r);
    }
}

// ---------------------------------------------------------------------------
// dwconv3x3 + BN + add (final conv). Weights in registers (fixed c4/thread).
// ---------------------------------------------------------------------------
__global__ __launch_bounds__(256) void dwconv_bn_add_kernel(
    const float* __restrict__ in,     // [B][56][56][C]
    const float* __restrict__ wT,     // [9][C]
    const float* __restrict__ scv,    // [C]
    const float* __restrict__ shv,    // [C]
    const float* __restrict__ add_,   // [B][56][56][C]
    float* __restrict__ out)
{
    const int tid = threadIdx.x;
    const int c4  = tid & 63;
    const int wv  = tid >> 6;
    const int c0  = c4 * 4;
    float4 wr[9];
#pragma unroll
    for (int t = 0; t < 9; ++t) wr[t] = *(const float4*)(wT + t * C_ + c0);
    const float4 sc = *(const float4*)(scv + c0);
    const float4 sh = *(const float4*)(shv + c0);

    const int npix = B_ * N_TOK;
    for (int pix = blockIdx.x * 4 + wv; pix < npix; pix += gridDim.x * 4) {
        int bb  = pix / N_TOK;
        int rem = pix - bb * N_TOK;
        int y   = rem / W_IMG;
        int x   = rem - y * W_IMG;
        const float* inb = in + (size_t)bb * N_TOK * C_;
        float cx = 0.f, cy = 0.f, cz = 0.f, cw = 0.f;
#pragma unroll
        for (int dy = -1; dy <= 1; ++dy) {
            int yy = y + dy;
            if (yy < 0 || yy >= H_IMG) continue;
#pragma unroll
            for (int dx = -1; dx <= 1; ++dx) {
                int xx = x + dx;
                if (xx < 0 || xx >= W_IMG) continue;
                const float4 iv = *(const float4*)(inb + (size_t)(yy * W_IMG + xx) * C_ + c0);
                const float4 w  = wr[(dy + 1) * 3 + (dx + 1)];
                cx = fmaf(iv.x, w.x, cx);
                cy = fmaf(iv.y, w.y, cy);
                cz = fmaf(iv.z, w.z, cz);
                cw = fmaf(iv.w, w.w, cw);
            }
        }
        const float4 av = *(const float4*)(add_ + (size_t)pix * C_ + c0);
        *(float4*)(out + (size_t)pix * C_ + c0) = make_float4(
            cx * sc.x + sh.x + av.x, cy * sc.y + sh.y + av.y,
            cz * sc.z + sh.z + av.z, cw * sc.w + sh.w + av.w);
    }
}

// ---------------------------------------------------------------------------
// Per-(b,head) logits: A[i][j] = scale * dot32(q[b,i,h*32:], k[b,j,h*32:])
// ---------------------------------------------------------------------------
__global__ __launch_bounds__(256) void qk_kernel(
    const float* __restrict__ q,   // [B][64][C]
    const float* __restrict__ k,   // [B][64][C]
    float* __restrict__ attnL)     // [B*8][64][64]
{
    int bh = blockIdx.x;
    int b = bh >> 3, head = bh & 7;
    __shared__ float qs[64][33];
    __shared__ float ks[64][33];
    int tid = threadIdx.x;
    for (int t = tid; t < 512; t += 256) {
        int i = t >> 3, dq = (t & 7) * 4;
        const float4 qv = *(const float4*)(q + ((size_t)(b * 64 + i) * C_ + head * 32 + dq));
        const float4 kv = *(const float4*)(k + ((size_t)(b * 64 + i) * C_ + head * 32 + dq));
        qs[i][dq + 0] = qv.x; qs[i][dq + 1] = qv.y; qs[i][dq + 2] = qv.z; qs[i][dq + 3] = qv.w;
        ks[i][dq + 0] = kv.x; ks[i][dq + 1] = kv.y; ks[i][dq + 2] = kv.z; ks[i][dq + 3] = kv.w;
    }
    __syncthreads();
    int i  = tid >> 2;
    int jb = (tid & 3) * 16;
    float qr[32];
#pragma unroll
    for (int d = 0; d < 32; ++d) qr[d] = qs[i][d];
    float* outp = attnL + (size_t)bh * 4096 + i * 64 + jb;
#pragma unroll
    for (int j = 0; j < 16; ++j) {
        float s = 0.f;
#pragma unroll
        for (int d = 0; d < 32; ++d) s = fmaf(qr[d], ks[jb + j][d], s);
        outp[j] = s * 0.0625f;   // C^-0.5 = 1/16
    }
}

// ---------------------------------------------------------------------------
// Fused upsample(logits)->softmax-weights->PV partial sums.
// Block = (b, head, chunk of 7 image rows). Threads: 64 rows x 4 d-groups.
// Row max of upsampled logits == row max of raw logits (grid points exact,
// interp is convex) -> single pass, accumulate Z and o simultaneously.
// ---------------------------------------------------------------------------
__global__ __launch_bounds__(256) void attn_pv_kernel(
    const float* __restrict__ attnL,  // [BH][64][64]
    const float* __restrict__ v,      // [B][3136][256]
    float* __restrict__ part_o,       // [BH][NCH][64][32]
    float* __restrict__ part_z)       // [BH][NCH][64]
{
    int blk   = blockIdx.x;
    int chunk = blk % NCH;
    int bh    = blk / NCH;
    int b = bh >> 3, head = bh & 7;
    __shared__ float Al[64][64];
    __shared__ float mrow[64];
    __shared__ float RY[64][10];      // [i][0..8], entry 8 duplicates 7
    __shared__ float Vrow[56][32];
    __shared__ float txs[56];
    __shared__ int   x0s[56];
    int tid = threadIdx.x;

    {
        const float4* src = (const float4*)(attnL + (size_t)bh * 4096);
        float4* dst = (float4*)&Al[0][0];
        for (int t = tid; t < 1024; t += 256) dst[t] = src[t];
    }
    if (tid < 56) {
        int i0, i1; float t;
        up_coef(tid, i0, i1, t);
        x0s[tid] = i0;
        txs[tid] = t;
    }
    __syncthreads();
    if (tid < 64) {
        float m = Al[tid][0];
        for (int j = 1; j < 64; ++j) m = fmaxf(m, Al[tid][j]);
        mrow[tid] = m;
    }
    __syncthreads();

    int i  = tid >> 2;   // query row 0..63
    int dg = tid & 3;    // d-group (8 channels each)
    float4 o0 = make_float4(0,0,0,0), o1 = make_float4(0,0,0,0);
    float z = 0.f;

    for (int r = 0; r < 7; ++r) {
        int y = chunk * 7 + r;
        __syncthreads();   // protect Vrow/RY from previous iteration readers
        for (int t = tid; t < 448; t += 256) {
            int xx = t >> 3, dq = (t & 7) << 2;
            *(float4*)&Vrow[xx][dq] =
                *(const float4*)(v + ((size_t)b * N_TOK + y * W_IMG + xx) * C_ + head * 32 + dq);
        }
        int y0, y1; float ty;
        up_coef(y, y0, y1, ty);
        for (int kk = dg; kk < 9; kk += 4) {
            int ks = kk < 8 ? kk : 7;
            float a0 = Al[i][y0 * 8 + ks];
            float a1 = Al[i][y1 * 8 + ks];
            RY[i][kk] = a0 + ty * (a1 - a0) - mrow[i];
        }
        __syncthreads();
        for (int x = 0; x < 56; ++x) {
            float tx = txs[x];
            int   x0 = x0s[x];
            float r0 = RY[i][x0], r1 = RY[i][x0 + 1];
            float l = r0 + tx * (r1 - r0);
            float wgt = __expf(l);
            z += wgt;
            const float4 v0 = *(const float4*)&Vrow[x][dg * 8];
            const float4 v1 = *(const float4*)&Vrow[x][dg * 8 + 4];
            o0.x = fmaf(wgt, v0.x, o0.x); o0.y = fmaf(wgt, v0.y, o0.y);
            o0.z = fmaf(wgt, v0.z, o0.z); o0.w = fmaf(wgt, v0.w, o0.w);
            o1.x = fmaf(wgt, v1.x, o1.x); o1.y = fmaf(wgt, v1.y, o1.y);
            o1.z = fmaf(wgt, v1.z, o1.z); o1.w = fmaf(wgt, v1.w, o1.w);
        }
    }

    size_t base = (((size_t)bh * NCH + chunk) * 64 + i) * 32 + dg * 8;
    *(float4*)(part_o + base)     = o0;
    *(float4*)(part_o + base + 4) = o1;
    if (dg == 0) part_z[((size_t)bh * NCH + chunk) * 64 + i] = z;
}

// ---------------------------------------------------------------------------
// Combine partials -> o_small [B][64][C] (NHWC, c = head*32+d), divide by Z.
// ---------------------------------------------------------------------------
__global__ __launch_bounds__(256) void combine_kernel(
    const float* __restrict__ part_o, const float* __restrict__ part_z,
    float* __restrict__ o_small)
{
    int idx = blockIdx.x * 256 + threadIdx.x;  // B*64*C
    if (idx >= B_ * 64 * C_) return;
    int c = idx % C_;
    int g = (idx / C_) % 64;
    int b = idx / (C_ * 64);
    int head = c >> 5, d = c & 31;
    int bh = b * 8 + head;
    float oo = 0.f, zz = 0.f;
    for (int ch = 0; ch < NCH; ++ch) {
        oo += part_o[(((size_t)bh * NCH + ch) * 64 + g) * 32 + d];
        zz += part_z[((size_t)bh * NCH + ch) * 64 + g];
    }
    o_small[idx] = oo / zz;
}

// ---------------------------------------------------------------------------
// Bilinear upsample 8x8 -> 56x56, NHWC.
// ---------------------------------------------------------------------------
__global__ __launch_bounds__(256) void upsample7_kernel(
    const float* __restrict__ in,   // [B][8][8][C]
    float* __restrict__ out)        // [B][56][56][C]
{
    int idx = blockIdx.x * 256 + threadIdx.x;  // per float4
    int c4  = idx % C4_;
    int pix = idx / C4_;
    int x = pix % W_IMG;
    int y = (pix / W_IMG) % H_IMG;
    int b = pix / (W_IMG * H_IMG);
    if (b >= B_) return;
    int y0, y1, x0, x1; float ty, tx;
    up_coef(y, y0, y1, ty);
    up_coef(x, x0, x1, tx);
    const float* base = in + (size_t)b * 64 * C_ + c4 * 4;
    const float4 v00 = *(const float4*)(base + (y0 * 8 + x0) * C_);
    const float4 v01 = *(const float4*)(base + (y0 * 8 + x1) * C_);
    const float4 v10 = *(const float4*)(base + (y1 * 8 + x0) * C_);
    const float4 v11 = *(const float4*)(base + (y1 * 8 + x1) * C_);
    float r0x = v00.x + tx * (v01.x - v00.x), r1x = v10.x + tx * (v11.x - v10.x);
    float r0y = v00.y + tx * (v01.y - v00.y), r1y = v10.y + tx * (v11.y - v10.y);
    float r0z = v00.z + tx * (v01.z - v00.z), r1z = v10.z + tx * (v11.z - v10.z);
    float r0w = v00.w + tx * (v01.w - v00.w), r1w = v10.w + tx * (v11.w - v10.w);
    *(float4*)(out + (size_t)idx * 4) = make_float4(
        r0x + ty * (r1x - r0x), r0y + ty * (r1y - r0y),
        r0z + ty * (r1z - r0z), r0w + ty * (r1w - r0w));
}

// ---------------------------------------------------------------------------
extern "C" void kernel_launch(void* const* d_in, const int* in_sizes, int n_in,
                              void* d_out, int out_size, void* d_ws, size_t ws_size,
                              hipStream_t stream)
{
    const float* x    = (const float*)d_in[0];
    const float* Wv   = (const float*)d_in[1];
    const float* c1w  = (const float*)d_in[2];
    const float* b1g  = (const float*)d_in[3];
    const float* b1b  = (const float*)d_in[4];
    const float* b1m  = (const float*)d_in[5];
    const float* b1v  = (const float*)d_in[6];
    const float* c2w  = (const float*)d_in[7];
    const float* b2g  = (const float*)d_in[8];
    const float* b2b  = (const float*)d_in[9];
    const float* b2m  = (const float*)d_in[10];
    const float* b2v  = (const float*)d_in[11];
    const float* vupw = (const float*)d_in[12];
    const float* b3g  = (const float*)d_in[13];
    const float* b3b  = (const float*)d_in[14];
    const float* b3m  = (const float*)d_in[15];
    const float* b3v  = (const float*)d_in[16];
    const float* Wp   = (const float*)d_in[17];
    const float* bp   = (const float*)d_in[18];
    float* out = (float*)d_out;
    float* ws  = (float*)d_ws;

    const size_t SZ = (size_t)B_ * N_TOK * C_;      // 12,845,056 floats
    float* v       = ws;
    float* s1g     = v   + SZ;                       // gelu(bn1(conv1(v)))
    float* s2g     = s1g + SZ;                       // gelu(bn2(conv2(s1g))) = skip_tok
    float* q       = s2g + SZ;                       // B*64*C
    float* kk      = q  + (size_t)B_ * 64 * C_;
    float* attnL   = kk + (size_t)B_ * 64 * C_;      // B*8*64*64
    float* part_o  = attnL  + (size_t)B_ * 8 * 64 * 64;
    float* part_z  = part_o + (size_t)B_ * 8 * NCH * 64 * 32;
    float* o_small = part_z + (size_t)B_ * 8 * NCH * 64;
    float* wT1     = o_small + (size_t)B_ * 64 * C_;
    float* wT2     = wT1 + 9 * C_;
    float* wT3     = wT2 + 9 * C_;
    float* sc1     = wT3 + 9 * C_;
    float* sh1     = sc1 + C_;
    float* sc2     = sh1 + C_;
    float* sh2     = sc2 + C_;
    float* sc3     = sh2 + C_;
    float* sh3     = sc3 + C_;

    const int M = B_ * N_TOK;                        // 50176
    const int pix_blocks = B_ * N_TOK / 4;           // 12544

    // 0. fold BN, transpose weights
    prep_kernel<<<1, 256, 0, stream>>>(c1w, c2w, vupw,
        b1g, b1b, b1m, b1v, b2g, b2b, b2m, b2v, b3g, b3b, b3m, b3v,
        wT1, wT2, wT3, sc1, sh1, sc2, sh2, sc3, sh3);
    // 1. v = x @ Wv^T
    gemm_nt_kernel<<<(M / 128) * (C_ / 128), 256, 0, stream>>>(x, Wv, nullptr, v, M, C_, C_);
    // 2. s1g = gelu(bn1(conv1(v))), q = avgpool(bn1(conv1(v)))
    dwconv_bn_pool_gelu_kernel<<<512, 256, 0, stream>>>(v, wT1, sc1, sh1, s1g, q);
    // 3. s2g = gelu(bn2(conv2(s1g))), k = avgpool(bn2(conv2(s1g)))
    dwconv_bn_pool_gelu_kernel<<<512, 256, 0, stream>>>(s1g, wT2, sc2, sh2, s2g, kk);
    // 4. logits (scaled)
    qk_kernel<<<B_ * 8, 256, 0, stream>>>(q, kk, attnL);
    // 5. fused upsample+softmax-weights+PV partials
    attn_pv_kernel<<<B_ * 8 * NCH, 256, 0, stream>>>(attnL, v, part_o, part_z);
    // 6. combine -> o_small [B][8][8][C]
    combine_kernel<<<B_ * 64 * C_ / 256, 256, 0, stream>>>(part_o, part_z, o_small);
    // 7. upsample o_small -> full res (reuse s1g, dead after step 3)
    upsample7_kernel<<<pix_blocks, 256, 0, stream>>>(o_small, s1g);
    // 8. t = bn3(conv3(up)) + s2g   (into v, dead after step 5)
    dwconv_bn_add_kernel<<<1024, 256, 0, stream>>>(s1g, wT3, sc3, sh3, s2g, v);
    // 9. out = t @ Wp^T + bp
    gemm_nt_kernel<<<(M / 128) * (C_ / 128), 256, 0, stream>>>(v, Wp, bp, out, M, C_, C_);
}

// Round 3
// 355.829 us; speedup vs baseline: 1.9301x; 1.3352x over previous
//
#include <hip/hip_runtime.h>
#include <math.h>

// Problem constants (LocallyEnhancedAttention: B=16, N=3136, C=256, SR=7, HEADS=8)
#define B_     16
#define H_IMG  56
#define W_IMG  56
#define N_TOK  3136      // 56*56
#define C_     256
#define C4_    64        // C_/4
#define NHEAD  8
#define HDIM   32
#define NCH    8         // attn pixel chunks (each = 7 image rows = 392 pixels)

typedef float f32x4 __attribute__((ext_vector_type(4)));
typedef __bf16 bf16x8 __attribute__((ext_vector_type(8)));

__device__ __forceinline__ float geluf(float x) {
    // jax.nn.gelu(approximate=False) = x * 0.5 * (1 + erf(x/sqrt(2)))
    return 0.5f * x * (1.0f + erff(x * 0.70710678118654752f));
}

// 8 -> 56 bilinear (half-pixel + edge renormalize == index clamp).
// f = (o-3)/7
__device__ __forceinline__ void up_coef(int o, int& i0, int& i1, float& t) {
    float f  = (float)(o - 3) * (1.0f / 7.0f);
    float fl = floorf(f);
    int   ii = (int)fl;
    t = f - fl;
    if (ii < 0)       { i0 = 0; i1 = 0; t = 0.0f; }
    else if (ii >= 7) { i0 = 7; i1 = 7; t = 0.0f; }
    else              { i0 = ii; i1 = ii + 1; }
}

// Split fp32 -> bf16 hi (truncate) + bf16 lo (truncate of exact remainder).
// hi+lo reproduces x to ~2^-17 relative; A*B via 3 MFMA terms ~2^-16.
__device__ __forceinline__ void split_bf16(float4 f, uint2& hi, uint2& lo) {
    unsigned u0 = __float_as_uint(f.x), u1 = __float_as_uint(f.y);
    unsigned u2 = __float_as_uint(f.z), u3 = __float_as_uint(f.w);
    unsigned h0 = u0 & 0xFFFF0000u, h1 = u1 & 0xFFFF0000u;
    unsigned h2 = u2 & 0xFFFF0000u, h3 = u3 & 0xFFFF0000u;
    hi = make_uint2((h0 >> 16) | h1, (h2 >> 16) | h3);
    float l0 = f.x - __uint_as_float(h0);
    float l1 = f.y - __uint_as_float(h1);
    float l2 = f.z - __uint_as_float(h2);
    float l3 = f.w - __uint_as_float(h3);
    lo = make_uint2((__float_as_uint(l0) >> 16) | (__float_as_uint(l1) & 0xFFFF0000u),
                    (__float_as_uint(l2) >> 16) | (__float_as_uint(l3) & 0xFFFF0000u));
}

// ---------------------------------------------------------------------------
// Prep: transpose dw weights [C][9] -> [9][C]; fold BN into scale/shift.
// ---------------------------------------------------------------------------
__global__ void prep_kernel(
    const float* __restrict__ w1, const float* __restrict__ w2, const float* __restrict__ w3,
    const float* __restrict__ g1, const float* __restrict__ b1, const float* __restrict__ m1, const float* __restrict__ v1,
    const float* __restrict__ g2, const float* __restrict__ b2, const float* __restrict__ m2, const float* __restrict__ v2,
    const float* __restrict__ g3, const float* __restrict__ b3, const float* __restrict__ m3, const float* __restrict__ v3,
    float* __restrict__ wT1, float* __restrict__ wT2, float* __restrict__ wT3,
    float* __restrict__ sc1, float* __restrict__ sh1,
    float* __restrict__ sc2, float* __restrict__ sh2,
    float* __restrict__ sc3, float* __restrict__ sh3)
{
    int c = threadIdx.x;   // 256 threads, 1 block
#pragma unroll
    for (int t = 0; t < 9; ++t) {
        wT1[t * C_ + c] = w1[c * 9 + t];
        wT2[t * C_ + c] = w2[c * 9 + t];
        wT3[t * C_ + c] = w3[c * 9 + t];
    }
    float s1 = g1[c] * rsqrtf(v1[c] + 1e-5f); sc1[c] = s1; sh1[c] = b1[c] - m1[c] * s1;
    float s2 = g2[c] * rsqrtf(v2[c] + 1e-5f); sc2[c] = s2; sh2[c] = b2[c] - m2[c] * s2;
    float s3 = g3[c] * rsqrtf(v3[c] + 1e-5f); sc3[c] = s3; sh3[c] = b3[c] - m3[c] * s3;
}

// ---------------------------------------------------------------------------
// MFMA GEMM (NT): C[m,n] = sum_k A[m,k]*Bm[n,k] (+bias[n]), fp32 in/out.
// Split-bf16: 3 MFMA terms (hi*hi + hi*lo + lo*hi) per fragment.
// BM=BN=128, BK=32, 256 thr (4 waves, 2x2), wave tile 64x64 (4x4 frags).
// LDS rows padded to 40 bf16 (20 dwords) -> 2-way bank aliasing (free).
// ---------------------------------------------------------------------------
#define AHI 0
#define ALO 2560
#define BHI 5120
#define BLO 7680
__global__ __launch_bounds__(256) void gemm_nt_mfma_kernel(
    const float* __restrict__ A,    // [M][K]
    const float* __restrict__ Bm,   // [N][K]
    const float* __restrict__ bias, // [N] or nullptr
    float* __restrict__ C,          // [M][N]
    int M, int N, int K)
{
    __shared__ unsigned lds[10240];   // 40 KB
    const int tid  = threadIdx.x;
    const int nb   = N >> 7;
    const int bx   = blockIdx.x % nb;
    const int by   = blockIdx.x / nb;
    const int lane = tid & 63;
    const int wv   = tid >> 6;        // wave 0..3
    const int wr   = wv >> 1, wc = wv & 1;
    const int l15  = lane & 15, kb = lane >> 4;

    const int srow = tid >> 1;             // 0..127
    const int sdw  = (tid & 1) * 8;        // dword offset within row (16 bf16)
    const float* Ap = A  + (size_t)(by * 128 + srow) * K + (tid & 1) * 16;
    const float* Bp = Bm + (size_t)(bx * 128 + srow) * K + (tid & 1) * 16;

    f32x4 acc[4][4];
#pragma unroll
    for (int m = 0; m < 4; ++m)
#pragma unroll
        for (int n = 0; n < 4; ++n) acc[m][n] = (f32x4)(0.0f);

    for (int k0 = 0; k0 < K; k0 += 32) {
        float4 a[4], b[4];
#pragma unroll
        for (int i = 0; i < 4; ++i) a[i] = *(const float4*)(Ap + k0 + i * 4);
#pragma unroll
        for (int i = 0; i < 4; ++i) b[i] = *(const float4*)(Bp + k0 + i * 4);
        __syncthreads();
        {
            uint2 h[4], l[4];
#pragma unroll
            for (int i = 0; i < 4; ++i) split_bf16(a[i], h[i], l[i]);
            *(uint4*)&lds[AHI + srow * 20 + sdw]     = make_uint4(h[0].x, h[0].y, h[1].x, h[1].y);
            *(uint4*)&lds[AHI + srow * 20 + sdw + 4] = make_uint4(h[2].x, h[2].y, h[3].x, h[3].y);
            *(uint4*)&lds[ALO + srow * 20 + sdw]     = make_uint4(l[0].x, l[0].y, l[1].x, l[1].y);
            *(uint4*)&lds[ALO + srow * 20 + sdw + 4] = make_uint4(l[2].x, l[2].y, l[3].x, l[3].y);
#pragma unroll
            for (int i = 0; i < 4; ++i) split_bf16(b[i], h[i], l[i]);
            *(uint4*)&lds[BHI + srow * 20 + sdw]     = make_uint4(h[0].x, h[0].y, h[1].x, h[1].y);
            *(uint4*)&lds[BHI + srow * 20 + sdw + 4] = make_uint4(h[2].x, h[2].y, h[3].x, h[3].y);
            *(uint4*)&lds[BLO + srow * 20 + sdw]     = make_uint4(l[0].x, l[0].y, l[1].x, l[1].y);
            *(uint4*)&lds[BLO + srow * 20 + sdw + 4] = make_uint4(l[2].x, l[2].y, l[3].x, l[3].y);
        }
        __syncthreads();

        bf16x8 ah[4], al[4], bh[4], bl[4];
#pragma unroll
        for (int m = 0; m < 4; ++m) {
            int r = wr * 64 + m * 16 + l15;
            ah[m] = *(const bf16x8*)&lds[AHI + r * 20 + kb * 4];
            al[m] = *(const bf16x8*)&lds[ALO + r * 20 + kb * 4];
        }
#pragma unroll
        for (int n = 0; n < 4; ++n) {
            int r = wc * 64 + n * 16 + l15;
            bh[n] = *(const bf16x8*)&lds[BHI + r * 20 + kb * 4];
            bl[n] = *(const bf16x8*)&lds[BLO + r * 20 + kb * 4];
        }
#pragma unroll
        for (int m = 0; m < 4; ++m)
#pragma unroll
            for (int n = 0; n < 4; ++n) {
                acc[m][n] = __builtin_amdgcn_mfma_f32_16x16x32_bf16(ah[m], bh[n], acc[m][n], 0, 0, 0);
                acc[m][n] = __builtin_amdgcn_mfma_f32_16x16x32_bf16(ah[m], bl[n], acc[m][n], 0, 0, 0);
                acc[m][n] = __builtin_amdgcn_mfma_f32_16x16x32_bf16(al[m], bh[n], acc[m][n], 0, 0, 0);
            }
    }

    // C/D layout (m89-verified): col = lane&15, row = (lane>>4)*4 + reg
    const int rb = by * 128 + wr * 64 + kb * 4;
    const int cb = bx * 128 + wc * 64 + l15;
#pragma unroll
    for (int n = 0; n < 4; ++n) {
        int col = cb + n * 16;
        float bv = bias ? bias[col] : 0.0f;
#pragma unroll
        for (int m = 0; m < 4; ++m) {
            int row = rb + m * 16;
#pragma unroll
            for (int r = 0; r < 4; ++r)
                C[(size_t)(row + r) * N + col] = acc[m][n][r] + bv;
        }
    }
}

// ---------------------------------------------------------------------------
// Fused: dwconv3x3 + BN, then (a) 7x7 avgpool of the BN output (pre-gelu)
// accumulated in LDS -> pool_out, and (b) gelu(BN output) -> outg (full res).
// Block = (b, gy, gx-pair): 7 rows x 14 cols x 64 c4-groups. 256 threads:
// wave = one pixel's 64 channel-quads -> weights/BN live in registers.
// ---------------------------------------------------------------------------
__global__ __launch_bounds__(256) void dwconv_bn_pool_gelu_kernel(
    const float* __restrict__ in,     // [B][56][56][C]
    const float* __restrict__ wT,     // [9][C]
    const float* __restrict__ scv,    // [C]
    const float* __restrict__ shv,    // [C]
    float* __restrict__ outg,         // [B][56][56][C]  gelu(bn(conv))
    float* __restrict__ pool)         // [B][64][C]      avgpool of bn(conv)
{
    const int blk = blockIdx.x;
    const int gxp = blk & 3;
    const int gy  = (blk >> 2) & 7;
    const int b   = blk >> 5;
    const int tid = threadIdx.x;
    const int c4  = tid & 63;
    const int wv  = tid >> 6;
    const int c0  = c4 * 4;

    float4 wr[9];
#pragma unroll
    for (int t = 0; t < 9; ++t) wr[t] = *(const float4*)(wT + t * C_ + c0);
    const float4 sc = *(const float4*)(scv + c0);
    const float4 sh = *(const float4*)(shv + c0);

    const int x0 = gxp * 14, y0 = gy * 7;
    const float* inb = in + (size_t)b * N_TOK * C_;
    float4 a0 = make_float4(0, 0, 0, 0), a1 = make_float4(0, 0, 0, 0);

    for (int p = wv; p < 98; p += 4) {
        int py = p / 14, px = p - py * 14;
        int y = y0 + py, x = x0 + px;
        float cx = 0.f, cy = 0.f, cz = 0.f, cw = 0.f;
#pragma unroll
        for (int dy = -1; dy <= 1; ++dy) {
            int yy = y + dy;
            if (yy < 0 || yy >= H_IMG) continue;
#pragma unroll
            for (int dx = -1; dx <= 1; ++dx) {
                int xx = x + dx;
                if (xx < 0 || xx >= W_IMG) continue;
                const float4 iv = *(const float4*)(inb + (size_t)(yy * W_IMG + xx) * C_ + c0);
                const float4 w  = wr[(dy + 1) * 3 + (dx + 1)];
                cx = fmaf(iv.x, w.x, cx);
                cy = fmaf(iv.y, w.y, cy);
                cz = fmaf(iv.z, w.z, cz);
                cw = fmaf(iv.w, w.w, cw);
            }
        }
        float vx = cx * sc.x + sh.x;
        float vy = cy * sc.y + sh.y;
        float vz = cz * sc.z + sh.z;
        float vw = cw * sc.w + sh.w;
        if (px < 7) { a0.x += vx; a0.y += vy; a0.z += vz; a0.w += vw; }
        else        { a1.x += vx; a1.y += vy; a1.z += vz; a1.w += vw; }
        *(float4*)(outg + ((size_t)b * N_TOK + y * W_IMG + x) * C_ + c0) =
            make_float4(geluf(vx), geluf(vy), geluf(vz), geluf(vw));
    }

    __shared__ float4 ps[4][2][64];
    ps[wv][0][c4] = a0;
    ps[wv][1][c4] = a1;
    __syncthreads();
    if (tid < 128) {
        int wi = tid >> 6, cc = tid & 63;
        float4 s  = ps[0][wi][cc];
        float4 t1 = ps[1][wi][cc];
        float4 t2 = ps[2][wi][cc];
        float4 t3 = ps[3][wi][cc];
        const float r = 1.0f / 49.0f;
        int g = gy * 8 + gxp * 2 + wi;
        *(float4*)(pool + ((size_t)b * 64 + g) * C_ + cc * 4) = make_float4(
            (s.x + t1.x + t2.x + t3.x) * r, (s.y + t1.y + t2.y + t3.y) * r,
            (s.z + t1.z + t2.z + t3.z) * r, (s.w + t1.w + t2.w + t3.w) * r);
    }
}

// ---------------------------------------------------------------------------
// dwconv3x3 + BN + add (final conv). Weights in registers (fixed c4/thread).
// ---------------------------------------------------------------------------
__global__ __launch_bounds__(256) void dwconv_bn_add_kernel(
    const float* __restrict__ in,     // [B][56][56][C]
    const float* __restrict__ wT,     // [9][C]
    const float* __restrict__ scv,    // [C]
    const float* __restrict__ shv,    // [C]
    const float* __restrict__ add_,   // [B][56][56][C]
    float* __restrict__ out)
{
    const int tid = threadIdx.x;
    const int c4  = tid & 63;
    const int wv  = tid >> 6;
    const int c0  = c4 * 4;
    float4 wr[9];
#pragma unroll
    for (int t = 0; t < 9; ++t) wr[t] = *(const float4*)(wT + t * C_ + c0);
    const float4 sc = *(const float4*)(scv + c0);
    const float4 sh = *(const float4*)(shv + c0);

    const int npix = B_ * N_TOK;
    for (int pix = blockIdx.x * 4 + wv; pix < npix; pix += gridDim.x * 4) {
        int bb  = pix / N_TOK;
        int rem = pix - bb * N_TOK;
        int y   = rem / W_IMG;
        int x   = rem - y * W_IMG;
        const float* inb = in + (size_t)bb * N_TOK * C_;
        float cx = 0.f, cy = 0.f, cz = 0.f, cw = 0.f;
#pragma unroll
        for (int dy = -1; dy <= 1; ++dy) {
            int yy = y + dy;
            if (yy < 0 || yy >= H_IMG) continue;
#pragma unroll
            for (int dx = -1; dx <= 1; ++dx) {
                int xx = x + dx;
                if (xx < 0 || xx >= W_IMG) continue;
                const float4 iv = *(const float4*)(inb + (size_t)(yy * W_IMG + xx) * C_ + c0);
                const float4 w  = wr[(dy + 1) * 3 + (dx + 1)];
                cx = fmaf(iv.x, w.x, cx);
                cy = fmaf(iv.y, w.y, cy);
                cz = fmaf(iv.z, w.z, cz);
                cw = fmaf(iv.w, w.w, cw);
            }
        }
        const float4 av = *(const float4*)(add_ + (size_t)pix * C_ + c0);
        *(float4*)(out + (size_t)pix * C_ + c0) = make_float4(
            cx * sc.x + sh.x + av.x, cy * sc.y + sh.y + av.y,
            cz * sc.z + sh.z + av.z, cw * sc.w + sh.w + av.w);
    }
}

// ---------------------------------------------------------------------------
// Per-(b,head) logits: A[i][j] = scale * dot32(q[b,i,h*32:], k[b,j,h*32:])
// ---------------------------------------------------------------------------
__global__ __launch_bounds__(256) void qk_kernel(
    const float* __restrict__ q,   // [B][64][C]
    const float* __restrict__ k,   // [B][64][C]
    float* __restrict__ attnL)     // [B*8][64][64]
{
    int bh = blockIdx.x;
    int b = bh >> 3, head = bh & 7;
    __shared__ float qs[64][33];
    __shared__ float ks[64][33];
    int tid = threadIdx.x;
    for (int t = tid; t < 512; t += 256) {
        int i = t >> 3, dq = (t & 7) * 4;
        const float4 qv = *(const float4*)(q + ((size_t)(b * 64 + i) * C_ + head * 32 + dq));
        const float4 kv = *(const float4*)(k + ((size_t)(b * 64 + i) * C_ + head * 32 + dq));
        qs[i][dq + 0] = qv.x; qs[i][dq + 1] = qv.y; qs[i][dq + 2] = qv.z; qs[i][dq + 3] = qv.w;
        ks[i][dq + 0] = kv.x; ks[i][dq + 1] = kv.y; ks[i][dq + 2] = kv.z; ks[i][dq + 3] = kv.w;
    }
    __syncthreads();
    int i  = tid >> 2;
    int jb = (tid & 3) * 16;
    float qr[32];
#pragma unroll
    for (int d = 0; d < 32; ++d) qr[d] = qs[i][d];
    float* outp = attnL + (size_t)bh * 4096 + i * 64 + jb;
#pragma unroll
    for (int j = 0; j < 16; ++j) {
        float s = 0.f;
#pragma unroll
        for (int d = 0; d < 32; ++d) s = fmaf(qr[d], ks[jb + j][d], s);
        outp[j] = s * 0.0625f;   // C^-0.5 = 1/16
    }
}

// ---------------------------------------------------------------------------
// Fused upsample(logits)->softmax-weights->PV partial sums.
// Block = (b, head, chunk of 7 image rows). Threads: 64 rows x 4 d-groups.
// Row max of upsampled logits == row max of raw logits (grid points exact,
// interp is convex) -> single pass, accumulate Z and o simultaneously.
// ---------------------------------------------------------------------------
__global__ __launch_bounds__(256) void attn_pv_kernel(
    const float* __restrict__ attnL,  // [BH][64][64]
    const float* __restrict__ v,      // [B][3136][256]
    float* __restrict__ part_o,       // [BH][NCH][64][32]
    float* __restrict__ part_z)       // [BH][NCH][64]
{
    int blk   = blockIdx.x;
    int chunk = blk % NCH;
    int bh    = blk / NCH;
    int b = bh >> 3, head = bh & 7;
    __shared__ float Al[64][64];
    __shared__ float mrow[64];
    __shared__ float RY[64][10];      // [i][0..8], entry 8 duplicates 7
    __shared__ float Vrow[56][32];
    __shared__ float txs[56];
    __shared__ int   x0s[56];
    int tid = threadIdx.x;

    {
        const float4* src = (const float4*)(attnL + (size_t)bh * 4096);
        float4* dst = (float4*)&Al[0][0];
        for (int t = tid; t < 1024; t += 256) dst[t] = src[t];
    }
    if (tid < 56) {
        int i0, i1; float t;
        up_coef(tid, i0, i1, t);
        x0s[tid] = i0;
        txs[tid] = t;
    }
    __syncthreads();
    if (tid < 64) {
        float m = Al[tid][0];
        for (int j = 1; j < 64; ++j) m = fmaxf(m, Al[tid][j]);
        mrow[tid] = m;
    }
    __syncthreads();

    int i  = tid >> 2;   // query row 0..63
    int dg = tid & 3;    // d-group (8 channels each)
    float4 o0 = make_float4(0,0,0,0), o1 = make_float4(0,0,0,0);
    float z = 0.f;

    for (int r = 0; r < 7; ++r) {
        int y = chunk * 7 + r;
        __syncthreads();   // protect Vrow/RY from previous iteration readers
        for (int t = tid; t < 448; t += 256) {
            int xx = t >> 3, dq = (t & 7) << 2;
            *(float4*)&Vrow[xx][dq] =
                *(const float4*)(v + ((size_t)b * N_TOK + y * W_IMG + xx) * C_ + head * 32 + dq);
        }
        int y0, y1; float ty;
        up_coef(y, y0, y1, ty);
        for (int kk = dg; kk < 9; kk += 4) {
            int ks = kk < 8 ? kk : 7;
            float a0 = Al[i][y0 * 8 + ks];
            float a1 = Al[i][y1 * 8 + ks];
            RY[i][kk] = a0 + ty * (a1 - a0) - mrow[i];
        }
        __syncthreads();
        for (int x = 0; x < 56; ++x) {
            float tx = txs[x];
            int   x0 = x0s[x];
            float r0 = RY[i][x0], r1 = RY[i][x0 + 1];
            float l = r0 + tx * (r1 - r0);
            float wgt = __expf(l);
            z += wgt;
            const float4 v0 = *(const float4*)&Vrow[x][dg * 8];
            const float4 v1 = *(const float4*)&Vrow[x][dg * 8 + 4];
            o0.x = fmaf(wgt, v0.x, o0.x); o0.y = fmaf(wgt, v0.y, o0.y);
            o0.z = fmaf(wgt, v0.z, o0.z); o0.w = fmaf(wgt, v0.w, o0.w);
            o1.x = fmaf(wgt, v1.x, o1.x); o1.y = fmaf(wgt, v1.y, o1.y);
            o1.z = fmaf(wgt, v1.z, o1.z); o1.w = fmaf(wgt, v1.w, o1.w);
        }
    }

    size_t base = (((size_t)bh * NCH + chunk) * 64 + i) * 32 + dg * 8;
    *(float4*)(part_o + base)     = o0;
    *(float4*)(part_o + base + 4) = o1;
    if (dg == 0) part_z[((size_t)bh * NCH + chunk) * 64 + i] = z;
}

// ---------------------------------------------------------------------------
// Combine partials -> o_small [B][64][C] (NHWC, c = head*32+d), divide by Z.
// ---------------------------------------------------------------------------
__global__ __launch_bounds__(256) void combine_kernel(
    const float* __restrict__ part_o, const float* __restrict__ part_z,
    float* __restrict__ o_small)
{
    int idx = blockIdx.x * 256 + threadIdx.x;  // B*64*C
    if (idx >= B_ * 64 * C_) return;
    int c = idx % C_;
    int g = (idx / C_) % 64;
    int b = idx / (C_ * 64);
    int head = c >> 5, d = c & 31;
    int bh = b * 8 + head;
    float oo = 0.f, zz = 0.f;
    for (int ch = 0; ch < NCH; ++ch) {
        oo += part_o[(((size_t)bh * NCH + ch) * 64 + g) * 32 + d];
        zz += part_z[((size_t)bh * NCH + ch) * 64 + g];
    }
    o_small[idx] = oo / zz;
}

// ---------------------------------------------------------------------------
// Bilinear upsample 8x8 -> 56x56, NHWC.
// ---------------------------------------------------------------------------
__global__ __launch_bounds__(256) void upsample7_kernel(
    const float* __restrict__ in,   // [B][8][8][C]
    float* __restrict__ out)        // [B][56][56][C]
{
    int idx = blockIdx.x * 256 + threadIdx.x;  // per float4
    int c4  = idx % C4_;
    int pix = idx / C4_;
    int x = pix % W_IMG;
    int y = (pix / W_IMG) % H_IMG;
    int b = pix / (W_IMG * H_IMG);
    if (b >= B_) return;
    int y0, y1, x0, x1; float ty, tx;
    up_coef(y, y0, y1, ty);
    up_coef(x, x0, x1, tx);
    const float* base = in + (size_t)b * 64 * C_ + c4 * 4;
    const float4 v00 = *(const float4*)(base + (y0 * 8 + x0) * C_);
    const float4 v01 = *(const float4*)(base + (y0 * 8 + x1) * C_);
    const float4 v10 = *(const float4*)(base + (y1 * 8 + x0) * C_);
    const float4 v11 = *(const float4*)(base + (y1 * 8 + x1) * C_);
    float r0x = v00.x + tx * (v01.x - v00.x), r1x = v10.x + tx * (v11.x - v10.x);
    float r0y = v00.y + tx * (v01.y - v00.y), r1y = v10.y + tx * (v11.y - v10.y);
    float r0z = v00.z + tx * (v01.z - v00.z), r1z = v10.z + tx * (v11.z - v10.z);
    float r0w = v00.w + tx * (v01.w - v00.w), r1w = v10.w + tx * (v11.w - v10.w);
    *(float4*)(out + (size_t)idx * 4) = make_float4(
        r0x + ty * (r1x - r0x), r0y + ty * (r1y - r0y),
        r0z + ty * (r1z - r0z), r0w + ty * (r1w - r0w));
}

// ---------------------------------------------------------------------------
extern "C" void kernel_launch(void* const* d_in, const int* in_sizes, int n_in,
                              void* d_out, int out_size, void* d_ws, size_t ws_size,
                              hipStream_t stream)
{
    const float* x    = (const float*)d_in[0];
    const float* Wv   = (const float*)d_in[1];
    const float* c1w  = (const float*)d_in[2];
    const float* b1g  = (const float*)d_in[3];
    const float* b1b  = (const float*)d_in[4];
    const float* b1m  = (const float*)d_in[5];
    const float* b1v  = (const float*)d_in[6];
    const float* c2w  = (const float*)d_in[7];
    const float* b2g  = (const float*)d_in[8];
    const float* b2b  = (const float*)d_in[9];
    const float* b2m  = (const float*)d_in[10];
    const float* b2v  = (const float*)d_in[11];
    const float* vupw = (const float*)d_in[12];
    const float* b3g  = (const float*)d_in[13];
    const float* b3b  = (const float*)d_in[14];
    const float* b3m  = (const float*)d_in[15];
    const float* b3v  = (const float*)d_in[16];
    const float* Wp   = (const float*)d_in[17];
    const float* bp   = (const float*)d_in[18];
    float* out = (float*)d_out;
    float* ws  = (float*)d_ws;

    const size_t SZ = (size_t)B_ * N_TOK * C_;      // 12,845,056 floats
    float* v       = ws;
    float* s1g     = v   + SZ;                       // gelu(bn1(conv1(v)))
    float* s2g     = s1g + SZ;                       // gelu(bn2(conv2(s1g))) = skip_tok
    float* q       = s2g + SZ;                       // B*64*C
    float* kk      = q  + (size_t)B_ * 64 * C_;
    float* attnL   = kk + (size_t)B_ * 64 * C_;      // B*8*64*64
    float* part_o  = attnL  + (size_t)B_ * 8 * 64 * 64;
    float* part_z  = part_o + (size_t)B_ * 8 * NCH * 64 * 32;
    float* o_small = part_z + (size_t)B_ * 8 * NCH * 64;
    float* wT1     = o_small + (size_t)B_ * 64 * C_;
    float* wT2     = wT1 + 9 * C_;
    float* wT3     = wT2 + 9 * C_;
    float* sc1     = wT3 + 9 * C_;
    float* sh1     = sc1 + C_;
    float* sc2     = sh1 + C_;
    float* sh2     = sc2 + C_;
    float* sc3     = sh2 + C_;
    float* sh3     = sc3 + C_;

    const int M = B_ * N_TOK;                        // 50176
    const int pix_blocks = B_ * N_TOK / 4;           // 12544

    // 0. fold BN, transpose weights
    prep_kernel<<<1, 256, 0, stream>>>(c1w, c2w, vupw,
        b1g, b1b, b1m, b1v, b2g, b2b, b2m, b2v, b3g, b3b, b3m, b3v,
        wT1, wT2, wT3, sc1, sh1, sc2, sh2, sc3, sh3);
    // 1. v = x @ Wv^T   (MFMA split-bf16)
    gemm_nt_mfma_kernel<<<(M / 128) * (C_ / 128), 256, 0, stream>>>(x, Wv, nullptr, v, M, C_, C_);
    // 2. s1g = gelu(bn1(conv1(v))), q = avgpool(bn1(conv1(v)))
    dwconv_bn_pool_gelu_kernel<<<512, 256, 0, stream>>>(v, wT1, sc1, sh1, s1g, q);
    // 3. s2g = gelu(bn2(conv2(s1g))), k = avgpool(bn2(conv2(s1g)))
    dwconv_bn_pool_gelu_kernel<<<512, 256, 0, stream>>>(s1g, wT2, sc2, sh2, s2g, kk);
    // 4. logits (scaled)
    qk_kernel<<<B_ * 8, 256, 0, stream>>>(q, kk, attnL);
    // 5. fused upsample+softmax-weights+PV partials
    attn_pv_kernel<<<B_ * 8 * NCH, 256, 0, stream>>>(attnL, v, part_o, part_z);
    // 6. combine -> o_small [B][8][8][C]
    combine_kernel<<<B_ * 64 * C_ / 256, 256, 0, stream>>>(part_o, part_z, o_small);
    // 7. upsample o_small -> full res (reuse s1g, dead after step 3)
    upsample7_kernel<<<pix_blocks, 256, 0, stream>>>(o_small, s1g);
    // 8. t = bn3(conv3(up)) + s2g   (into v, dead after step 5)
    dwconv_bn_add_kernel<<<1024, 256, 0, stream>>>(s1g, wT3, sc3, sh3, s2g, v);
    // 9. out = t @ Wp^T + bp   (MFMA split-bf16)
    gemm_nt_mfma_kernel<<<(M / 128) * (C_ / 128), 256, 0, stream>>>(v, Wp, bp, out, M, C_, C_);
}